// Round 17
// baseline (152.371 us; speedup 1.0000x reference)
//
#include <hip/hip_runtime.h>
#include <hip/hip_bf16.h>

#define NFEAT 256
#define NHID  128
#define NPB   128    // nodes per bucket (dst >> 7)
#define BMAX  2048   // max buckets (n_nodes <= 256K)
#define SCHUNK 2048  // edges per scatter block (compile-time for unroll)

typedef short s16x8 __attribute__((ext_vector_type(8)));
typedef float f32x4 __attribute__((ext_vector_type(4)));
typedef float f32x2 __attribute__((ext_vector_type(2)));

static __device__ __forceinline__ ushort bfbits(float f) {
  __hip_bfloat16 h = __float2bfloat16(f);
  return *reinterpret_cast<ushort*>(&h);
}

// role mapping: proportional interleave of role0 (count0) and role1 (count1)
static __device__ __forceinline__ void role_map(int idx, int count0, int count1,
                                                int& role, int& sub) {
  const long long total = (long long)count0 + count1;
  const int c_lo = (int)((long long)idx * count0 / total);
  const int c_hi = (int)(((long long)idx + 1) * count0 / total);
  if (c_hi > c_lo) { role = 0; sub = c_lo; }
  else             { role = 1; sub = idx - c_hi; }
}

// ---------------------------------------------------------------------------
// GEMM tile body (proven R12 form): BM=64 x NHID=128, K chunks of 64,
// XOR-swizzled LDS, 24 KB.  Shared by the fused kernels.
// ---------------------------------------------------------------------------
__device__ __forceinline__ void gemm_tile(
    const float* __restrict__ x, const ushort* __restrict__ Wt,
    ushort* __restrict__ sup, int n_nodes, int rowBase,
    ushort* As, ushort* Bs) {
  const int t = threadIdx.x;
  const int wid = t >> 6;
  const int lane = t & 63;
  if (rowBase >= n_nodes) return;

  f32x4 acc[4][2];
#pragma unroll
  for (int m = 0; m < 4; ++m)
#pragma unroll
    for (int n = 0; n < 2; ++n) acc[m][n] = (f32x4){0.f, 0.f, 0.f, 0.f};

  const float4* x4 = (const float4*)x;

  for (int kc = 0; kc < 4; ++kc) {
    __syncthreads();
#pragma unroll
    for (int it = 0; it < 4; ++it) {
      const int i4 = t + it * 256;
      const int r = i4 >> 4, k4 = i4 & 15;
      const int row = rowBase + r;
      float4 v = make_float4(0.f, 0.f, 0.f, 0.f);
      if (row < n_nodes) v = x4[(size_t)row * (NFEAT / 4) + kc * 16 + k4];
      ushort4 h;
      h.x = bfbits(v.x); h.y = bfbits(v.y); h.z = bfbits(v.z); h.w = bfbits(v.w);
      int byte = (r << 7) + (k4 << 3);
      byte ^= (r & 7) << 4;
      *(ushort4*)((char*)As + byte) = h;
    }
#pragma unroll
    for (int it = 0; it < 8; ++it) {
      const int i2 = t + it * 256;
      const int col = i2 >> 4, k4 = i2 & 15;
      const ushort4 h = *(const ushort4*)(Wt + col * NFEAT + kc * 64 + k4 * 4);
      int byte = (col << 7) + (k4 << 3);
      byte ^= (col & 7) << 4;
      *(ushort4*)((char*)Bs + byte) = h;
    }
    __syncthreads();
#pragma unroll
    for (int ks = 0; ks < 2; ++ks) {
      const int k0 = ks * 32 + (lane >> 4) * 8;
      s16x8 af[4], bfr[2];
#pragma unroll
      for (int m = 0; m < 4; ++m) {
        const int r = m * 16 + (lane & 15);
        int byte = (r << 7) + (k0 << 1);
        byte ^= (r & 7) << 4;
        af[m] = *(const s16x8*)((const char*)As + byte);
      }
#pragma unroll
      for (int n = 0; n < 2; ++n) {
        const int c = wid * 32 + n * 16 + (lane & 15);
        int byte = (c << 7) + (k0 << 1);
        byte ^= (c & 7) << 4;
        bfr[n] = *(const s16x8*)((const char*)Bs + byte);
      }
#pragma unroll
      for (int m = 0; m < 4; ++m)
#pragma unroll
        for (int n = 0; n < 2; ++n)
          acc[m][n] = __builtin_amdgcn_mfma_f32_16x16x32_bf16(af[m], bfr[n], acc[m][n], 0, 0, 0);
    }
  }

  // C/D layout: col = lane&15, row = (lane>>4)*4 + reg   [m89-verified]
#pragma unroll
  for (int m = 0; m < 4; ++m) {
#pragma unroll
    for (int rr = 0; rr < 4; ++rr) {
      const int row = rowBase + m * 16 + (lane >> 4) * 4 + rr;
      if (row < n_nodes) {
#pragma unroll
        for (int n = 0; n < 2; ++n) {
          const int col = wid * 32 + n * 16 + (lane & 15);
          sup[(size_t)row * NHID + col] = bfbits(acc[m][n][rr]);
        }
      }
    }
  }
}

// ---------------------------------------------------------------------------
// W transpose+convert: Wt[n][k] = bf16(W[k][n])   (standalone, tiny)
// ---------------------------------------------------------------------------
__global__ __launch_bounds__(256) void wcvt_kernel(
    const float* __restrict__ W, ushort* __restrict__ Wt) {
  const int id = blockIdx.x * 256 + threadIdx.x;
  const int k = id >> 7, n = id & 127;
  Wt[n * NFEAT + k] = bfbits(W[id]);
}

// ---------------------------------------------------------------------------
// Fused 1: bucket histogram (role 0, LDS atomics, hist aliases As) ||
// GEMM rows [0, n1*64).
// ---------------------------------------------------------------------------
__global__ __launch_bounds__(256) void fused1_kernel(
    const float* __restrict__ x, const ushort* __restrict__ Wt,
    ushort* __restrict__ sup, int n_nodes,
    const int* __restrict__ edst, int* __restrict__ histT,
    int n_edges, int B, int G, int n1) {
  __shared__ ushort As[64 * 64];   // 8 KB (hist role aliases as hist[2048])
  __shared__ ushort Bs[128 * 64];  // 16 KB

  int role, sub;
  role_map(blockIdx.x, G, n1, role, sub);

  if (role == 0) {
    int* hist = (int*)As;
    const int g = sub;
    for (int b = threadIdx.x; b < B; b += 256) hist[b] = 0;
    __syncthreads();
    const int e0 = g * SCHUNK;
    const int e1 = (e0 + SCHUNK < n_edges) ? e0 + SCHUNK : n_edges;
    for (int e = e0 + threadIdx.x; e < e1; e += 256)
      atomicAdd(&hist[(uint)edst[e] >> 7], 1);  // LDS atomic
    __syncthreads();
    for (int b = threadIdx.x; b < B; b += 256) histT[(size_t)b * G + g] = hist[b];
    return;
  }

  gemm_tile(x, Wt, sup, n_nodes, sub * 64, As, Bs);
}

// ---------------------------------------------------------------------------
// Hierarchical exclusive scan (over histT, n = B*G, up to ~1M)
// ---------------------------------------------------------------------------
__global__ __launch_bounds__(256) void scan1_kernel(
    const int* __restrict__ in, int* __restrict__ exc,
    int* __restrict__ bsums, int n) {
  const int tid = threadIdx.x;
  const int lane = tid & 63, wid = tid >> 6;
  const int base = blockIdx.x * 1024 + tid * 4;
  int v0 = 0, v1 = 0, v2 = 0, v3 = 0;
  if (base + 3 < n) {
    int4 v = *(const int4*)(in + base);
    v0 = v.x; v1 = v.y; v2 = v.z; v3 = v.w;
  } else {
    if (base + 0 < n) v0 = in[base + 0];
    if (base + 1 < n) v1 = in[base + 1];
    if (base + 2 < n) v2 = in[base + 2];
  }
  const int tsum = v0 + v1 + v2 + v3;
  int t = tsum;
#pragma unroll
  for (int d = 1; d < 64; d <<= 1) {
    int u = __shfl_up(t, d);
    if (lane >= d) t += u;
  }
  __shared__ int wtot[4], wpre[4];
  if (lane == 63) wtot[wid] = t;
  __syncthreads();
  if (tid == 0) {
    int s = 0;
    for (int w = 0; w < 4; ++w) { wpre[w] = s; s += wtot[w]; }
    bsums[blockIdx.x] = s;
  }
  __syncthreads();
  const int off = (t - tsum) + wpre[wid];
  if (base + 0 < n) exc[base + 0] = off;
  if (base + 1 < n) exc[base + 1] = off + v0;
  if (base + 2 < n) exc[base + 2] = off + v0 + v1;
  if (base + 3 < n) exc[base + 3] = off + v0 + v1 + v2;
}

// single block, loops over bsums in chunks of 256 with running carry
__global__ __launch_bounds__(256) void scan2_kernel(int* __restrict__ bsums, int nb) {
  __shared__ int wtot[4], wpre[4], tot_s;
  const int tid = threadIdx.x;
  const int lane = tid & 63, wid = tid >> 6;
  int carry = 0;
  for (int base = 0; base < nb; base += 256) {
    const int idx = base + tid;
    const int v = (idx < nb) ? bsums[idx] : 0;
    int t = v;
#pragma unroll
    for (int d = 1; d < 64; d <<= 1) {
      int u = __shfl_up(t, d);
      if (lane >= d) t += u;
    }
    if (lane == 63) wtot[wid] = t;
    __syncthreads();
    if (tid == 0) {
      int s = 0;
      for (int w = 0; w < 4; ++w) { wpre[w] = s; s += wtot[w]; }
      tot_s = s;
    }
    __syncthreads();
    if (idx < nb) bsums[idx] = carry + (t - v) + wpre[wid];
    carry += tot_s;
    __syncthreads();
  }
}

// finalize offsets; emit bucket_start[] and transposed baseT[g*B + b]
__global__ __launch_bounds__(256) void scan3_kernel(
    const int* __restrict__ exc, const int* __restrict__ bsums,
    int* __restrict__ baseT, int* __restrict__ bucket_start,
    int n, int G, int B, int n_edges) {
  const int i = blockIdx.x * 256 + threadIdx.x;
  if (i < n) {
    const int v = exc[i] + bsums[i >> 10];
    const int b = i / G, g = i % G;
    baseT[(size_t)g * B + b] = v;
    if (g == 0) bucket_start[b] = v;
  }
  if (i == 0) bucket_start[B] = n_edges;
}

// ---------------------------------------------------------------------------
// Fused 2: bucket-scatter (role 0, LDS cursors, unrolled x8) ||
// GEMM rows [n1*64, (n1+n2)*64).  packed2: .x = src | (dst&127)<<18.
// ---------------------------------------------------------------------------
__global__ __launch_bounds__(256) void fused2_kernel(
    const float* __restrict__ x, const ushort* __restrict__ Wt,
    ushort* __restrict__ sup, int n_nodes,
    const int* __restrict__ esrc, const int* __restrict__ edst,
    const float* __restrict__ ew, const int* __restrict__ baseT,
    int2* __restrict__ packed2, int n_edges, int B, int G, int n2, int gemm_base) {
  __shared__ ushort As[64 * 64];   // 8 KB (scatter role aliases as cursors)
  __shared__ ushort Bs[128 * 64];  // 16 KB

  int role, sub;
  role_map(blockIdx.x, G, n2, role, sub);

  if (role == 0) {
    int* cursor = (int*)As;  // up to 2048 ints
    const int g = sub;
    for (int b = threadIdx.x; b < B; b += 256) cursor[b] = baseT[(size_t)g * B + b];
    __syncthreads();
    const int e0 = g * SCHUNK;
    if (e0 + SCHUNK <= n_edges) {
      int d[8], s[8]; float w[8];
#pragma unroll
      for (int j = 0; j < 8; ++j) {
        const int e = e0 + j * 256 + threadIdx.x;
        d[j] = edst[e]; s[j] = esrc[e]; w[j] = ew[e];
      }
#pragma unroll
      for (int j = 0; j < 8; ++j) {
        const int pos = atomicAdd(&cursor[(uint)d[j] >> 7], 1);  // LDS atomic
        packed2[pos] = make_int2(s[j] | ((d[j] & (NPB - 1)) << 18), __float_as_int(w[j]));
      }
    } else {
      for (int e = e0 + threadIdx.x; e < n_edges; e += 256) {
        const int dst = edst[e];
        const int pos = atomicAdd(&cursor[(uint)dst >> 7], 1);
        packed2[pos] = make_int2(esrc[e] | ((dst & (NPB - 1)) << 18), __float_as_int(ew[e]));
      }
    }
    return;
  }

  gemm_tile(x, Wt, sup, n_nodes, (gemm_base + sub) * 64, As, Bs);
}

// ---------------------------------------------------------------------------
// Fused 3: bucket_build (role 0) || GEMM rows [(n1+n2)*64, ...).
// ---------------------------------------------------------------------------
__global__ __launch_bounds__(256) void fused3_kernel(
    const float* __restrict__ x, const ushort* __restrict__ Wt,
    ushort* __restrict__ sup, int n_nodes,
    const int2* __restrict__ packed2, const int* __restrict__ bucket_start,
    int2* __restrict__ packedN, int* __restrict__ row_start,
    int n_edges, int B, int n3, int gemm_base) {
  __shared__ ushort As[64 * 64];   // 8 KB
  __shared__ ushort Bs[128 * 64];  // 16 KB
  __shared__ int cnt[NPB];
  __shared__ int st[NPB];
  __shared__ int cur[NPB];
  __shared__ int w0tot;

  int role, sub;
  role_map(blockIdx.x, B, n3, role, sub);

  if (role == 0) {
    const int tid = threadIdx.x;
    const int b = sub;
    const int s0 = bucket_start[b];
    const int s1 = bucket_start[b + 1];
    const int m = s1 - s0;

    if (tid < NPB) cnt[tid] = 0;
    __syncthreads();

    for (int i = tid; i < m; i += 256)
      atomicAdd(&cnt[((uint)packed2[s0 + i].x >> 18) & (NPB - 1)], 1);
    __syncthreads();

    {
      const int v = (tid < NPB) ? cnt[tid] : 0;
      int t = v;
#pragma unroll
      for (int d = 1; d < 64; d <<= 1) {
        int u = __shfl_up(t, d);
        if ((tid & 63) >= d) t += u;
      }
      if (tid == 63) w0tot = t;
      __syncthreads();
      if (tid < NPB) {
        const int s = (t - v) + ((tid >= 64) ? w0tot : 0);
        st[tid] = s;
        cur[tid] = s;
      }
      __syncthreads();
    }

    for (int i = tid; i < m; i += 256) {
      const int2 e = packed2[s0 + i];
      const int dl = ((uint)e.x >> 18) & (NPB - 1);
      const int pos = atomicAdd(&cur[dl], 1);
      packedN[s0 + pos] = e;
    }

    if (tid < NPB) {
      const int node = b * NPB + tid;
      if (node < n_nodes) row_start[node] = s0 + st[tid];
    }
    if (b == 0 && tid == 0) row_start[n_nodes] = n_edges;
    return;
  }

  gemm_tile(x, Wt, sup, n_nodes, (gemm_base + sub) * 64, As, Bs);
}

// ---------------------------------------------------------------------------
// Aggregation (proven R12 form): 1 wave per node; lane owns 2 cols; SGPR-
// uniform edge loads; x8 unroll.  Fused bias + ReLU, NT float2 store.
// ---------------------------------------------------------------------------
__global__ __launch_bounds__(256) void agg_kernel(
    const ushort* __restrict__ sup, const int2* __restrict__ packed,
    const int* __restrict__ row_start, const float* __restrict__ bias,
    float* __restrict__ out, int n_nodes) {
  const int node = blockIdx.x * 4 + (threadIdx.x >> 6);
  if (node >= n_nodes) return;
  const int lane = threadIdx.x & 63;
  const int start = __builtin_amdgcn_readfirstlane(row_start[node]);
  const int end   = __builtin_amdgcn_readfirstlane(row_start[node + 1]);

  float a0 = 0.f, a1 = 0.f, b0 = 0.f, b1 = 0.f;
  float c0 = 0.f, c1 = 0.f, d0 = 0.f, d1 = 0.f;
  int i = start;
  for (; i + 7 < end; i += 8) {
    const int2 e0 = packed[i + 0];
    const int2 e1 = packed[i + 1];
    const int2 e2 = packed[i + 2];
    const int2 e3 = packed[i + 3];
    const int2 e4 = packed[i + 4];
    const int2 e5 = packed[i + 5];
    const int2 e6 = packed[i + 6];
    const int2 e7 = packed[i + 7];
    const uint u0 = *(const uint*)(sup + ((size_t)((uint)e0.x & 0x3FFFFu) << 7) + lane * 2);
    const uint u1 = *(const uint*)(sup + ((size_t)((uint)e1.x & 0x3FFFFu) << 7) + lane * 2);
    const uint u2 = *(const uint*)(sup + ((size_t)((uint)e2.x & 0x3FFFFu) << 7) + lane * 2);
    const uint u3 = *(const uint*)(sup + ((size_t)((uint)e3.x & 0x3FFFFu) << 7) + lane * 2);
    const uint u4 = *(const uint*)(sup + ((size_t)((uint)e4.x & 0x3FFFFu) << 7) + lane * 2);
    const uint u5 = *(const uint*)(sup + ((size_t)((uint)e5.x & 0x3FFFFu) << 7) + lane * 2);
    const uint u6 = *(const uint*)(sup + ((size_t)((uint)e6.x & 0x3FFFFu) << 7) + lane * 2);
    const uint u7 = *(const uint*)(sup + ((size_t)((uint)e7.x & 0x3FFFFu) << 7) + lane * 2);
    const float w0 = __int_as_float(e0.y), w1 = __int_as_float(e1.y);
    const float w2 = __int_as_float(e2.y), w3 = __int_as_float(e3.y);
    const float w4 = __int_as_float(e4.y), w5 = __int_as_float(e5.y);
    const float w6 = __int_as_float(e6.y), w7 = __int_as_float(e7.y);
    a0 += __uint_as_float(u0 << 16) * w0 + __uint_as_float(u4 << 16) * w4;
    a1 += __uint_as_float(u0 & 0xffff0000u) * w0 + __uint_as_float(u4 & 0xffff0000u) * w4;
    b0 += __uint_as_float(u1 << 16) * w1 + __uint_as_float(u5 << 16) * w5;
    b1 += __uint_as_float(u1 & 0xffff0000u) * w1 + __uint_as_float(u5 & 0xffff0000u) * w5;
    c0 += __uint_as_float(u2 << 16) * w2 + __uint_as_float(u6 << 16) * w6;
    c1 += __uint_as_float(u2 & 0xffff0000u) * w2 + __uint_as_float(u6 & 0xffff0000u) * w6;
    d0 += __uint_as_float(u3 << 16) * w3 + __uint_as_float(u7 << 16) * w7;
    d1 += __uint_as_float(u3 & 0xffff0000u) * w3 + __uint_as_float(u7 & 0xffff0000u) * w7;
  }
  for (; i + 3 < end; i += 4) {
    const int2 e0 = packed[i + 0];
    const int2 e1 = packed[i + 1];
    const int2 e2 = packed[i + 2];
    const int2 e3 = packed[i + 3];
    const uint u0 = *(const uint*)(sup + ((size_t)((uint)e0.x & 0x3FFFFu) << 7) + lane * 2);
    const uint u1 = *(const uint*)(sup + ((size_t)((uint)e1.x & 0x3FFFFu) << 7) + lane * 2);
    const uint u2 = *(const uint*)(sup + ((size_t)((uint)e2.x & 0x3FFFFu) << 7) + lane * 2);
    const uint u3 = *(const uint*)(sup + ((size_t)((uint)e3.x & 0x3FFFFu) << 7) + lane * 2);
    const float w0 = __int_as_float(e0.y), w1 = __int_as_float(e1.y);
    const float w2 = __int_as_float(e2.y), w3 = __int_as_float(e3.y);
    a0 += __uint_as_float(u0 << 16) * w0 + __uint_as_float(u2 << 16) * w2;
    a1 += __uint_as_float(u0 & 0xffff0000u) * w0 + __uint_as_float(u2 & 0xffff0000u) * w2;
    b0 += __uint_as_float(u1 << 16) * w1 + __uint_as_float(u3 << 16) * w3;
    b1 += __uint_as_float(u1 & 0xffff0000u) * w1 + __uint_as_float(u3 & 0xffff0000u) * w3;
  }
  for (; i < end; ++i) {
    const int2 e0 = packed[i];
    const uint u0 = *(const uint*)(sup + ((size_t)((uint)e0.x & 0x3FFFFu) << 7) + lane * 2);
    const float w0 = __int_as_float(e0.y);
    a0 += __uint_as_float(u0 << 16) * w0;
    a1 += __uint_as_float(u0 & 0xffff0000u) * w0;
  }

  const float2 bb = ((const float2*)bias)[lane];
  f32x2 r;
  r.x = fmaxf((a0 + b0) + (c0 + d0) + bb.x, 0.f);
  r.y = fmaxf((a1 + b1) + (c1 + d1) + bb.y, 0.f);
  __builtin_nontemporal_store(r, (f32x2*)out + (size_t)node * (NHID / 2) + lane);
}

// ---------------------------------------------------------------------------
// Fallback (ws too small): atomic scatter over bf16 support
// ---------------------------------------------------------------------------
__global__ __launch_bounds__(256) void scatter_bf16_kernel(
    const ushort* __restrict__ sup, const int* __restrict__ esrc,
    const int* __restrict__ edst, const float* __restrict__ ew,
    float* __restrict__ out, int n_edges) {
  const long long idx = (long long)blockIdx.x * 256 + threadIdx.x;
  const int e = (int)(idx >> 6);
  const int c2 = (int)(idx & 63);
  if (e >= n_edges) return;
  const int s = esrc[e];
  const int d = edst[e];
  const float wt = ew[e];
  const uint u = *(const uint*)(sup + (size_t)s * NHID + c2 * 2);
  float* drow = out + (size_t)d * NHID + c2 * 2;
  atomicAdd(drow + 0, __uint_as_float(u << 16) * wt);
  atomicAdd(drow + 1, __uint_as_float(u & 0xffff0000u) * wt);
}

__global__ __launch_bounds__(256) void gemm_only_kernel(
    const float* __restrict__ x, const ushort* __restrict__ Wt,
    ushort* __restrict__ sup, int n_nodes) {
  __shared__ ushort As[64 * 64];
  __shared__ ushort Bs[128 * 64];
  gemm_tile(x, Wt, sup, n_nodes, blockIdx.x * 64, As, Bs);
}

__global__ __launch_bounds__(256) void bias_relu_kernel(
    float* __restrict__ out, const float* __restrict__ b, int n4) {
  const int i = blockIdx.x * 256 + threadIdx.x;
  if (i >= n4) return;
  float4 v = ((float4*)out)[i];
  const float4 bb = ((const float4*)b)[i & (NHID / 4 - 1)];
  v.x = fmaxf(v.x + bb.x, 0.f);
  v.y = fmaxf(v.y + bb.y, 0.f);
  v.z = fmaxf(v.z + bb.z, 0.f);
  v.w = fmaxf(v.w + bb.w, 0.f);
  ((float4*)out)[i] = v;
}

static inline size_t align_up(size_t v, size_t a) { return (v + a - 1) & ~(a - 1); }

extern "C" void kernel_launch(void* const* d_in, const int* in_sizes, int n_in,
                              void* d_out, int out_size, void* d_ws, size_t ws_size,
                              hipStream_t stream) {
  const float* x    = (const float*)d_in[0];
  const int*   esrc = (const int*)d_in[1];
  const int*   edst = (const int*)d_in[2];
  const float* ew   = (const float*)d_in[3];
  const float* W    = (const float*)d_in[4];
  const float* b    = (const float*)d_in[5];
  float* out = (float*)d_out;

  const int n_nodes = in_sizes[0] / NFEAT;
  const int n_edges = in_sizes[1];

  // bucket geometry: B buckets of NPB nodes; G scatter chunks of SCHUNK
  const int B = (n_nodes + NPB - 1) / NPB;
  const int G = (n_edges + SCHUNK - 1) / SCHUNK;
  const long long n_scan_ll = (long long)B * G;

  // workspace layout (~63 MB at N=100k, E=1.6M)
  char* ws = (char*)d_ws;
  size_t off = 0;
  ushort* sup       = (ushort*)(ws + off); off = align_up(off + (size_t)n_nodes * NHID * 2, 256);
  ushort* Wt        = (ushort*)(ws + off); off = align_up(off + (size_t)NFEAT * NHID * 2, 256);
  int* histT        = (int*)(ws + off);    off = align_up(off + (size_t)B * G * 4, 256);
  int* exc          = (int*)(ws + off);    off = align_up(off + (size_t)B * G * 4, 256);
  int* baseT        = (int*)(ws + off);    off = align_up(off + (size_t)B * G * 4, 256);
  int* bsums        = (int*)(ws + off);    off = align_up(off + 1024 * 4, 256);
  int* bucket_start = (int*)(ws + off);    off = align_up(off + ((size_t)B + 1) * 4, 256);
  int* row_start    = (int*)(ws + off);    off = align_up(off + ((size_t)n_nodes + 1) * 4, 256);
  int2* packed2     = (int2*)(ws + off);   off = align_up(off + (size_t)n_edges * 8, 256);
  int2* packedN     = (int2*)(ws + off);   off = align_up(off + (size_t)n_edges * 8, 256);
  const bool csr_ok = (off <= ws_size) && (n_nodes <= 256 * 1024) && (B <= BMAX) &&
                      (n_scan_ll <= 1024 * 1024);

  const int n_gemm = (n_nodes + 63) / 64;
  // GEMM split matched to hidden work: hist ~20%, scatter ~50%, build ~30%
  const int n1 = n_gemm / 5;
  const int n2 = n_gemm / 2;
  const int n3 = n_gemm - n1 - n2;

  if (csr_ok) {
    // 0) Wt = bf16(W^T)  (GEMM dependency; tiny)
    wcvt_kernel<<<(NFEAT * NHID) / 256, 256, 0, stream>>>(W, Wt);

    // 1) hist || GEMM part1
    fused1_kernel<<<G + n1, 256, 0, stream>>>(
        x, Wt, sup, n_nodes, edst, histT, n_edges, B, G, n1);

    // 2) scan -> baseT (transposed) + bucket_start
    const int n_scan = (int)n_scan_ll;
    const int nb = (n_scan + 1023) / 1024;
    scan1_kernel<<<nb, 256, 0, stream>>>(histT, exc, bsums, n_scan);
    scan2_kernel<<<1, 256, 0, stream>>>(bsums, nb);
    scan3_kernel<<<(n_scan + 255) / 256, 256, 0, stream>>>(exc, bsums, baseT, bucket_start, n_scan, G, B, n_edges);

    // 3) scatter || GEMM part2
    fused2_kernel<<<G + n2, 256, 0, stream>>>(
        x, Wt, sup, n_nodes, esrc, edst, ew, baseT, packed2, n_edges, B, G, n2, n1);

    // 4) build || GEMM part3
    fused3_kernel<<<B + n3, 256, 0, stream>>>(
        x, Wt, sup, n_nodes, packed2, bucket_start, packedN, row_start,
        n_edges, B, n3, n1 + n2);

    // 5) full-TLP gather-sum + bias + relu
    agg_kernel<<<(n_nodes + 3) / 4, 256, 0, stream>>>(sup, packedN, row_start, b, out, n_nodes);
  } else {
    // fallback: minimal-ws path (sup + Wt only)
    wcvt_kernel<<<(NFEAT * NHID) / 256, 256, 0, stream>>>(W, Wt);
    gemm_only_kernel<<<n_gemm, 256, 0, stream>>>(x, Wt, sup, n_nodes);
    hipMemsetAsync(out, 0, (size_t)n_nodes * NHID * sizeof(float), stream);
    const long long threads = (long long)n_edges * 64;
    scatter_bf16_kernel<<<(int)((threads + 255) / 256), 256, 0, stream>>>(sup, esrc, edst, ew, out, n_edges);
    const int n4 = n_nodes * NHID / 4;
    bias_relu_kernel<<<(n4 + 255) / 256, 256, 0, stream>>>(out, b, n4);
  }
}

// Round 18
// 138.827 us; speedup vs baseline: 1.0976x; 1.0976x over previous
//
#include <hip/hip_runtime.h>
#include <hip/hip_bf16.h>

#define NFEAT 256
#define NHID  128
#define NPB   128    // nodes per bucket (dst >> 7)
#define BMAX  2048   // max buckets (n_nodes <= 256K)
#define SCHUNK 2048  // edges per scatter block (compile-time for unroll)

typedef short s16x8 __attribute__((ext_vector_type(8)));
typedef float f32x4 __attribute__((ext_vector_type(4)));
typedef float f32x2 __attribute__((ext_vector_type(2)));

static __device__ __forceinline__ ushort bfbits(float f) {
  __hip_bfloat16 h = __float2bfloat16(f);
  return *reinterpret_cast<ushort*>(&h);
}

// ---------------------------------------------------------------------------
// Prep: blocks 0..127 = W transpose+convert; blocks 128.. = bucket histogram
// via LDS atomics.  histT[b*G + g] = #edges of chunk g in bucket b.
// ---------------------------------------------------------------------------
__global__ __launch_bounds__(256) void prep_kernel(
    const float* __restrict__ W, ushort* __restrict__ Wt,
    const int* __restrict__ edst, int* __restrict__ histT,
    int n_edges, int B, int G) {
  __shared__ int hist[BMAX];
  if (blockIdx.x < 128) {
    const int id = blockIdx.x * 256 + threadIdx.x;
    const int k = id >> 7, n = id & 127;
    Wt[n * NFEAT + k] = bfbits(W[id]);
    return;
  }
  const int g = blockIdx.x - 128;
  for (int b = threadIdx.x; b < B; b += 256) hist[b] = 0;
  __syncthreads();
  const int e0 = g * SCHUNK;
  const int e1 = (e0 + SCHUNK < n_edges) ? e0 + SCHUNK : n_edges;
  for (int e = e0 + threadIdx.x; e < e1; e += 256)
    atomicAdd(&hist[(uint)edst[e] >> 7], 1);  // LDS atomic
  __syncthreads();
  for (int b = threadIdx.x; b < B; b += 256) histT[(size_t)b * G + g] = hist[b];
}

// ---------------------------------------------------------------------------
// Hierarchical exclusive scan (over histT, n = B*G, up to ~1M)
// ---------------------------------------------------------------------------
__global__ __launch_bounds__(256) void scan1_kernel(
    const int* __restrict__ in, int* __restrict__ exc,
    int* __restrict__ bsums, int n) {
  const int tid = threadIdx.x;
  const int lane = tid & 63, wid = tid >> 6;
  const int base = blockIdx.x * 1024 + tid * 4;
  int v0 = 0, v1 = 0, v2 = 0, v3 = 0;
  if (base + 3 < n) {
    int4 v = *(const int4*)(in + base);
    v0 = v.x; v1 = v.y; v2 = v.z; v3 = v.w;
  } else {
    if (base + 0 < n) v0 = in[base + 0];
    if (base + 1 < n) v1 = in[base + 1];
    if (base + 2 < n) v2 = in[base + 2];
  }
  const int tsum = v0 + v1 + v2 + v3;
  int t = tsum;
#pragma unroll
  for (int d = 1; d < 64; d <<= 1) {
    int u = __shfl_up(t, d);
    if (lane >= d) t += u;
  }
  __shared__ int wtot[4], wpre[4];
  if (lane == 63) wtot[wid] = t;
  __syncthreads();
  if (tid == 0) {
    int s = 0;
    for (int w = 0; w < 4; ++w) { wpre[w] = s; s += wtot[w]; }
    bsums[blockIdx.x] = s;
  }
  __syncthreads();
  const int off = (t - tsum) + wpre[wid];
  if (base + 0 < n) exc[base + 0] = off;
  if (base + 1 < n) exc[base + 1] = off + v0;
  if (base + 2 < n) exc[base + 2] = off + v0 + v1;
  if (base + 3 < n) exc[base + 3] = off + v0 + v1 + v2;
}

// single block, loops over bsums in chunks of 256 with running carry
__global__ __launch_bounds__(256) void scan2_kernel(int* __restrict__ bsums, int nb) {
  __shared__ int wtot[4], wpre[4], tot_s;
  const int tid = threadIdx.x;
  const int lane = tid & 63, wid = tid >> 6;
  int carry = 0;
  for (int base = 0; base < nb; base += 256) {
    const int idx = base + tid;
    const int v = (idx < nb) ? bsums[idx] : 0;
    int t = v;
#pragma unroll
    for (int d = 1; d < 64; d <<= 1) {
      int u = __shfl_up(t, d);
      if (lane >= d) t += u;
    }
    if (lane == 63) wtot[wid] = t;
    __syncthreads();
    if (tid == 0) {
      int s = 0;
      for (int w = 0; w < 4; ++w) { wpre[w] = s; s += wtot[w]; }
      tot_s = s;
    }
    __syncthreads();
    if (idx < nb) bsums[idx] = carry + (t - v) + wpre[wid];
    carry += tot_s;
    __syncthreads();
  }
}

// finalize offsets; emit bucket_start[] and transposed baseT[g*B + b]
__global__ __launch_bounds__(256) void scan3_kernel(
    const int* __restrict__ exc, const int* __restrict__ bsums,
    int* __restrict__ baseT, int* __restrict__ bucket_start,
    int n, int G, int B, int n_edges) {
  const int i = blockIdx.x * 256 + threadIdx.x;
  if (i < n) {
    const int v = exc[i] + bsums[i >> 10];
    const int b = i / G, g = i % G;
    baseT[(size_t)g * B + b] = v;
    if (g == 0) bucket_start[b] = v;
  }
  if (i == 0) bucket_start[B] = n_edges;
}

// ---------------------------------------------------------------------------
// Fused: bucket-scatter (role 0, LDS cursors, unrolled x8) || MFMA GEMM
// (role 1).  packed2: .x = src | (dst&127)<<18, .y = w bits.
// ---------------------------------------------------------------------------
__global__ __launch_bounds__(256) void gemm_scatter_fused(
    const float* __restrict__ x, const ushort* __restrict__ Wt,
    ushort* __restrict__ sup, int n_nodes,
    const int* __restrict__ esrc, const int* __restrict__ edst,
    const float* __restrict__ ew, const int* __restrict__ baseT,
    int2* __restrict__ packed2, int n_edges, int B, int G, int n_gemm) {
  __shared__ ushort As[64 * 64];   // 8 KB (scatter role aliases as cursors)
  __shared__ ushort Bs[128 * 64];  // 16 KB

  const int idx = blockIdx.x;
  const long long total = (long long)n_gemm + G;
  const int c_lo = (int)((long long)idx * G / total);
  const int c_hi = (int)(((long long)idx + 1) * G / total);
  int role, sub;
  if (c_hi > c_lo) { role = 0; sub = c_lo; }
  else             { role = 1; sub = idx - c_hi; }

  if (role == 0) {
    // ---- bucket scatter: coalesced cursor init from baseT ----
    int* cursor = (int*)As;  // up to 2048 ints
    const int g = sub;
    for (int b = threadIdx.x; b < B; b += 256) cursor[b] = baseT[(size_t)g * B + b];
    __syncthreads();
    const int e0 = g * SCHUNK;
    if (e0 + SCHUNK <= n_edges) {
      int d[8], s[8]; float w[8];
#pragma unroll
      for (int j = 0; j < 8; ++j) {
        const int e = e0 + j * 256 + threadIdx.x;
        d[j] = edst[e]; s[j] = esrc[e]; w[j] = ew[e];
      }
#pragma unroll
      for (int j = 0; j < 8; ++j) {
        const int pos = atomicAdd(&cursor[(uint)d[j] >> 7], 1);  // LDS atomic
        packed2[pos] = make_int2(s[j] | ((d[j] & (NPB - 1)) << 18), __float_as_int(w[j]));
      }
    } else {
      const int e1 = n_edges;
      for (int e = e0 + threadIdx.x; e < e1; e += 256) {
        const int dst = edst[e];
        const int pos = atomicAdd(&cursor[(uint)dst >> 7], 1);
        packed2[pos] = make_int2(esrc[e] | ((dst & (NPB - 1)) << 18), __float_as_int(ew[e]));
      }
    }
    return;
  }

  // ---- MFMA GEMM: BM=64 x NHID=128, K chunks of 64 ----
  const int t = threadIdx.x;
  const int wid = t >> 6;
  const int lane = t & 63;
  const int rowBase = sub * 64;
  if (rowBase >= n_nodes) return;

  f32x4 acc[4][2];
#pragma unroll
  for (int m = 0; m < 4; ++m)
#pragma unroll
    for (int n = 0; n < 2; ++n) acc[m][n] = (f32x4){0.f, 0.f, 0.f, 0.f};

  const float4* x4 = (const float4*)x;

  for (int kc = 0; kc < 4; ++kc) {
    __syncthreads();
#pragma unroll
    for (int it = 0; it < 4; ++it) {
      const int i4 = t + it * 256;
      const int r = i4 >> 4, k4 = i4 & 15;
      const int row = rowBase + r;
      float4 v = make_float4(0.f, 0.f, 0.f, 0.f);
      if (row < n_nodes) v = x4[(size_t)row * (NFEAT / 4) + kc * 16 + k4];
      ushort4 h;
      h.x = bfbits(v.x); h.y = bfbits(v.y); h.z = bfbits(v.z); h.w = bfbits(v.w);
      int byte = (r << 7) + (k4 << 3);
      byte ^= (r & 7) << 4;
      *(ushort4*)((char*)As + byte) = h;
    }
#pragma unroll
    for (int it = 0; it < 8; ++it) {
      const int i2 = t + it * 256;
      const int col = i2 >> 4, k4 = i2 & 15;
      const ushort4 h = *(const ushort4*)(Wt + col * NFEAT + kc * 64 + k4 * 4);
      int byte = (col << 7) + (k4 << 3);
      byte ^= (col & 7) << 4;
      *(ushort4*)((char*)Bs + byte) = h;
    }
    __syncthreads();
#pragma unroll
    for (int ks = 0; ks < 2; ++ks) {
      const int k0 = ks * 32 + (lane >> 4) * 8;
      s16x8 af[4], bfr[2];
#pragma unroll
      for (int m = 0; m < 4; ++m) {
        const int r = m * 16 + (lane & 15);
        int byte = (r << 7) + (k0 << 1);
        byte ^= (r & 7) << 4;
        af[m] = *(const s16x8*)((const char*)As + byte);
      }
#pragma unroll
      for (int n = 0; n < 2; ++n) {
        const int c = wid * 32 + n * 16 + (lane & 15);
        int byte = (c << 7) + (k0 << 1);
        byte ^= (c & 7) << 4;
        bfr[n] = *(const s16x8*)((const char*)Bs + byte);
      }
#pragma unroll
      for (int m = 0; m < 4; ++m)
#pragma unroll
        for (int n = 0; n < 2; ++n)
          acc[m][n] = __builtin_amdgcn_mfma_f32_16x16x32_bf16(af[m], bfr[n], acc[m][n], 0, 0, 0);
    }
  }

  // C/D layout: col = lane&15, row = (lane>>4)*4 + reg   [m89-verified]
#pragma unroll
  for (int m = 0; m < 4; ++m) {
#pragma unroll
    for (int rr = 0; rr < 4; ++rr) {
      const int row = rowBase + m * 16 + (lane >> 4) * 4 + rr;
      if (row < n_nodes) {
#pragma unroll
        for (int n = 0; n < 2; ++n) {
          const int col = wid * 32 + n * 16 + (lane & 15);
          sup[(size_t)row * NHID + col] = bfbits(acc[m][n][rr]);
        }
      }
    }
  }
}

// ---------------------------------------------------------------------------
// Per-bucket node-grouping -> packedN + row_start (global)
// ---------------------------------------------------------------------------
__global__ __launch_bounds__(256) void bucket_build_kernel(
    const int2* __restrict__ packed2, const int* __restrict__ bucket_start,
    int2* __restrict__ packedN, int* __restrict__ row_start,
    int n_nodes, int n_edges) {
  __shared__ int cnt[NPB];
  __shared__ int st[NPB];
  __shared__ int cur[NPB];
  __shared__ int w0tot;
  const int tid = threadIdx.x;
  const int b = blockIdx.x;
  const int s0 = bucket_start[b];
  const int s1 = bucket_start[b + 1];
  const int m = s1 - s0;

  if (tid < NPB) cnt[tid] = 0;
  __syncthreads();

  for (int i = tid; i < m; i += 256)
    atomicAdd(&cnt[((uint)packed2[s0 + i].x >> 18) & (NPB - 1)], 1);
  __syncthreads();

  {
    const int v = (tid < NPB) ? cnt[tid] : 0;
    int t = v;
#pragma unroll
    for (int d = 1; d < 64; d <<= 1) {
      int u = __shfl_up(t, d);
      if ((tid & 63) >= d) t += u;
    }
    if (tid == 63) w0tot = t;
    __syncthreads();
    if (tid < NPB) {
      const int s = (t - v) + ((tid >= 64) ? w0tot : 0);
      st[tid] = s;
      cur[tid] = s;
    }
    __syncthreads();
  }

  for (int i = tid; i < m; i += 256) {
    const int2 e = packed2[s0 + i];
    const int dl = ((uint)e.x >> 18) & (NPB - 1);
    const int pos = atomicAdd(&cur[dl], 1);
    packedN[s0 + pos] = e;
  }

  if (tid < NPB) {
    const int node = b * NPB + tid;
    if (node < n_nodes) row_start[node] = s0 + st[tid];
  }
  if (b == 0 && tid == 0) row_start[n_nodes] = n_edges;
}

// ---------------------------------------------------------------------------
// Aggregation (proven R12 form): 1 wave per node; lane owns 2 cols; SGPR-
// uniform edge loads; x8 unroll.  Fused bias + ReLU, NT float2 store.
// src = e.x & 0x3FFFF.
// ---------------------------------------------------------------------------
__global__ __launch_bounds__(256) void agg_kernel(
    const ushort* __restrict__ sup, const int2* __restrict__ packed,
    const int* __restrict__ row_start, const float* __restrict__ bias,
    float* __restrict__ out, int n_nodes) {
  const int node = blockIdx.x * 4 + (threadIdx.x >> 6);
  if (node >= n_nodes) return;
  const int lane = threadIdx.x & 63;
  const int start = __builtin_amdgcn_readfirstlane(row_start[node]);
  const int end   = __builtin_amdgcn_readfirstlane(row_start[node + 1]);

  float a0 = 0.f, a1 = 0.f, b0 = 0.f, b1 = 0.f;
  float c0 = 0.f, c1 = 0.f, d0 = 0.f, d1 = 0.f;
  int i = start;
  for (; i + 7 < end; i += 8) {
    const int2 e0 = packed[i + 0];
    const int2 e1 = packed[i + 1];
    const int2 e2 = packed[i + 2];
    const int2 e3 = packed[i + 3];
    const int2 e4 = packed[i + 4];
    const int2 e5 = packed[i + 5];
    const int2 e6 = packed[i + 6];
    const int2 e7 = packed[i + 7];
    const uint u0 = *(const uint*)(sup + ((size_t)((uint)e0.x & 0x3FFFFu) << 7) + lane * 2);
    const uint u1 = *(const uint*)(sup + ((size_t)((uint)e1.x & 0x3FFFFu) << 7) + lane * 2);
    const uint u2 = *(const uint*)(sup + ((size_t)((uint)e2.x & 0x3FFFFu) << 7) + lane * 2);
    const uint u3 = *(const uint*)(sup + ((size_t)((uint)e3.x & 0x3FFFFu) << 7) + lane * 2);
    const uint u4 = *(const uint*)(sup + ((size_t)((uint)e4.x & 0x3FFFFu) << 7) + lane * 2);
    const uint u5 = *(const uint*)(sup + ((size_t)((uint)e5.x & 0x3FFFFu) << 7) + lane * 2);
    const uint u6 = *(const uint*)(sup + ((size_t)((uint)e6.x & 0x3FFFFu) << 7) + lane * 2);
    const uint u7 = *(const uint*)(sup + ((size_t)((uint)e7.x & 0x3FFFFu) << 7) + lane * 2);
    const float w0 = __int_as_float(e0.y), w1 = __int_as_float(e1.y);
    const float w2 = __int_as_float(e2.y), w3 = __int_as_float(e3.y);
    const float w4 = __int_as_float(e4.y), w5 = __int_as_float(e5.y);
    const float w6 = __int_as_float(e6.y), w7 = __int_as_float(e7.y);
    a0 += __uint_as_float(u0 << 16) * w0 + __uint_as_float(u4 << 16) * w4;
    a1 += __uint_as_float(u0 & 0xffff0000u) * w0 + __uint_as_float(u4 & 0xffff0000u) * w4;
    b0 += __uint_as_float(u1 << 16) * w1 + __uint_as_float(u5 << 16) * w5;
    b1 += __uint_as_float(u1 & 0xffff0000u) * w1 + __uint_as_float(u5 & 0xffff0000u) * w5;
    c0 += __uint_as_float(u2 << 16) * w2 + __uint_as_float(u6 << 16) * w6;
    c1 += __uint_as_float(u2 & 0xffff0000u) * w2 + __uint_as_float(u6 & 0xffff0000u) * w6;
    d0 += __uint_as_float(u3 << 16) * w3 + __uint_as_float(u7 << 16) * w7;
    d1 += __uint_as_float(u3 & 0xffff0000u) * w3 + __uint_as_float(u7 & 0xffff0000u) * w7;
  }
  for (; i + 3 < end; i += 4) {
    const int2 e0 = packed[i + 0];
    const int2 e1 = packed[i + 1];
    const int2 e2 = packed[i + 2];
    const int2 e3 = packed[i + 3];
    const uint u0 = *(const uint*)(sup + ((size_t)((uint)e0.x & 0x3FFFFu) << 7) + lane * 2);
    const uint u1 = *(const uint*)(sup + ((size_t)((uint)e1.x & 0x3FFFFu) << 7) + lane * 2);
    const uint u2 = *(const uint*)(sup + ((size_t)((uint)e2.x & 0x3FFFFu) << 7) + lane * 2);
    const uint u3 = *(const uint*)(sup + ((size_t)((uint)e3.x & 0x3FFFFu) << 7) + lane * 2);
    const float w0 = __int_as_float(e0.y), w1 = __int_as_float(e1.y);
    const float w2 = __int_as_float(e2.y), w3 = __int_as_float(e3.y);
    a0 += __uint_as_float(u0 << 16) * w0 + __uint_as_float(u2 << 16) * w2;
    a1 += __uint_as_float(u0 & 0xffff0000u) * w0 + __uint_as_float(u2 & 0xffff0000u) * w2;
    b0 += __uint_as_float(u1 << 16) * w1 + __uint_as_float(u3 << 16) * w3;
    b1 += __uint_as_float(u1 & 0xffff0000u) * w1 + __uint_as_float(u3 & 0xffff0000u) * w3;
  }
  for (; i < end; ++i) {
    const int2 e0 = packed[i];
    const uint u0 = *(const uint*)(sup + ((size_t)((uint)e0.x & 0x3FFFFu) << 7) + lane * 2);
    const float w0 = __int_as_float(e0.y);
    a0 += __uint_as_float(u0 << 16) * w0;
    a1 += __uint_as_float(u0 & 0xffff0000u) * w0;
  }

  const float2 bb = ((const float2*)bias)[lane];
  f32x2 r;
  r.x = fmaxf((a0 + b0) + (c0 + d0) + bb.x, 0.f);
  r.y = fmaxf((a1 + b1) + (c1 + d1) + bb.y, 0.f);
  __builtin_nontemporal_store(r, (f32x2*)out + (size_t)node * (NHID / 2) + lane);
}

// ---------------------------------------------------------------------------
// Fallback (ws too small): atomic scatter over bf16 support
// ---------------------------------------------------------------------------
__global__ __launch_bounds__(256) void scatter_bf16_kernel(
    const ushort* __restrict__ sup, const int* __restrict__ esrc,
    const int* __restrict__ edst, const float* __restrict__ ew,
    float* __restrict__ out, int n_edges) {
  const long long idx = (long long)blockIdx.x * 256 + threadIdx.x;
  const int e = (int)(idx >> 6);
  const int c2 = (int)(idx & 63);
  if (e >= n_edges) return;
  const int s = esrc[e];
  const int d = edst[e];
  const float wt = ew[e];
  const uint u = *(const uint*)(sup + (size_t)s * NHID + c2 * 2);
  float* drow = out + (size_t)d * NHID + c2 * 2;
  atomicAdd(drow + 0, __uint_as_float(u << 16) * wt);
  atomicAdd(drow + 1, __uint_as_float(u & 0xffff0000u) * wt);
}

__global__ __launch_bounds__(256) void bias_relu_kernel(
    float* __restrict__ out, const float* __restrict__ b, int n4) {
  const int i = blockIdx.x * 256 + threadIdx.x;
  if (i >= n4) return;
  float4 v = ((float4*)out)[i];
  const float4 bb = ((const float4*)b)[i & (NHID / 4 - 1)];
  v.x = fmaxf(v.x + bb.x, 0.f);
  v.y = fmaxf(v.y + bb.y, 0.f);
  v.z = fmaxf(v.z + bb.z, 0.f);
  v.w = fmaxf(v.w + bb.w, 0.f);
  ((float4*)out)[i] = v;
}

static inline size_t align_up(size_t v, size_t a) { return (v + a - 1) & ~(a - 1); }

extern "C" void kernel_launch(void* const* d_in, const int* in_sizes, int n_in,
                              void* d_out, int out_size, void* d_ws, size_t ws_size,
                              hipStream_t stream) {
  const float* x    = (const float*)d_in[0];
  const int*   esrc = (const int*)d_in[1];
  const int*   edst = (const int*)d_in[2];
  const float* ew   = (const float*)d_in[3];
  const float* W    = (const float*)d_in[4];
  const float* b    = (const float*)d_in[5];
  float* out = (float*)d_out;

  const int n_nodes = in_sizes[0] / NFEAT;
  const int n_edges = in_sizes[1];

  // bucket geometry: B buckets of NPB nodes; G scatter chunks of SCHUNK
  const int B = (n_nodes + NPB - 1) / NPB;
  const int G = (n_edges + SCHUNK - 1) / SCHUNK;
  const long long n_scan_ll = (long long)B * G;

  // workspace layout (~63 MB at N=100k, E=1.6M)
  char* ws = (char*)d_ws;
  size_t off = 0;
  ushort* sup       = (ushort*)(ws + off); off = align_up(off + (size_t)n_nodes * NHID * 2, 256);
  ushort* Wt        = (ushort*)(ws + off); off = align_up(off + (size_t)NFEAT * NHID * 2, 256);
  int* histT        = (int*)(ws + off);    off = align_up(off + (size_t)B * G * 4, 256);
  int* exc          = (int*)(ws + off);    off = align_up(off + (size_t)B * G * 4, 256);
  int* baseT        = (int*)(ws + off);    off = align_up(off + (size_t)B * G * 4, 256);
  int* bsums        = (int*)(ws + off);    off = align_up(off + 1024 * 4, 256);
  int* bucket_start = (int*)(ws + off);    off = align_up(off + ((size_t)B + 1) * 4, 256);
  int* row_start    = (int*)(ws + off);    off = align_up(off + ((size_t)n_nodes + 1) * 4, 256);
  int2* packed2     = (int2*)(ws + off);   off = align_up(off + (size_t)n_edges * 8, 256);
  int2* packedN     = (int2*)(ws + off);   off = align_up(off + (size_t)n_edges * 8, 256);
  const bool csr_ok = (off <= ws_size) && (n_nodes <= 256 * 1024) && (B <= BMAX) &&
                      (n_scan_ll <= 1024 * 1024);

  const int n_gemm = (n_nodes + 63) / 64;

  if (csr_ok) {
    // 1) prep: Wt = bf16(W^T)  ||  bucket histogram
    prep_kernel<<<128 + G, 256, 0, stream>>>(W, Wt, edst, histT, n_edges, B, G);

    // 2) scan -> baseT (transposed) + bucket_start
    const int n_scan = (int)n_scan_ll;
    const int nb = (n_scan + 1023) / 1024;
    scan1_kernel<<<nb, 256, 0, stream>>>(histT, exc, bsums, n_scan);
    scan2_kernel<<<1, 256, 0, stream>>>(bsums, nb);
    scan3_kernel<<<(n_scan + 255) / 256, 256, 0, stream>>>(exc, bsums, baseT, bucket_start, n_scan, G, B, n_edges);

    // 3) fused bucket-scatter || MFMA GEMM
    gemm_scatter_fused<<<n_gemm + G, 256, 0, stream>>>(
        x, Wt, sup, n_nodes, esrc, edst, ew, baseT, packed2, n_edges, B, G, n_gemm);

    // 4) per-bucket node-grouping -> packedN + row_start
    bucket_build_kernel<<<B, 256, 0, stream>>>(
        packed2, bucket_start, packedN, row_start, n_nodes, n_edges);

    // 5) full-TLP gather-sum + bias + relu
    agg_kernel<<<(n_nodes + 3) / 4, 256, 0, stream>>>(sup, packedN, row_start, b, out, n_nodes);
  } else {
    // fallback: minimal-ws path (sup + Wt only), gemm role only
    prep_kernel<<<128, 256, 0, stream>>>(W, Wt, edst, (int*)d_ws, 0, 1, 1);
    gemm_scatter_fused<<<n_gemm, 256, 0, stream>>>(
        x, Wt, sup, n_nodes, esrc, edst, ew, (int*)d_ws, (int2*)d_ws,
        0, 1, 0, n_gemm);
    hipMemsetAsync(out, 0, (size_t)n_nodes * NHID * sizeof(float), stream);
    const long long threads = (long long)n_edges * 64;
    scatter_bf16_kernel<<<(int)((threads + 255) / 256), 256, 0, stream>>>(sup, esrc, edst, ew, out, n_edges);
    const int n4 = n_nodes * NHID / 4;
    bias_relu_kernel<<<(n4 + 255) / 256, 256, 0, stream>>>(out, b, n4);
  }
}